// Round 6
// baseline (27.233 us; speedup 1.0000x reference)
//
#include <hip/hip_runtime.h>

// Lanczos-4 8x upsample (4,2,256,256) -> (4,2,2048,2048), fully collapsed
// to a 2x2 bilinear-style stencil with 8 baked weight phases per axis
// (see R2-R5 history). R6: ONE OUTPUT ROW PER WAVE — each wave's 8 stores
// walk a contiguous 8 KB row sequentially (fill-kernel-like write stream,
// DRAM page locality), instead of 8 rows strided 8 KB apart.
// Vertical blend first (wave-uniform va,vb), then horizontal per lane.

// wa (left-column weight), per phase 0..7
#define WA0 0.0f
#define WA1 -0.03041110f
#define WA2 0.02753266f
#define WA3 -0.00827163f
#define WA4 1.00243180f
#define WA5 1.01040147f
#define WA6 0.97375330f
#define WA7 1.03080550f
// wb (right-column weight)
#define WB0 1.0f
#define WB1 1.02991210f
#define WB2 0.97065798f
#define WB3 1.00472265f
#define WB4 -0.00765906f
#define WB5 -0.01652347f
#define WB6 0.02047608f
#define WB7 -0.03455115f
// full tap sum (edge / reflected case: all 9 taps hit one source col/row)
#define WS0 1.0f
#define WS1 0.99950100f
#define WS2 0.99819064f
#define WS3 0.99645102f
#define WS4 0.99477274f
#define WS5 0.99387800f
#define WS6 0.99422938f
#define WS7 0.99625435f

__global__ __launch_bounds__(512) void lanczos_up8_kernel(
    const float* __restrict__ img, float* __restrict__ out)
{
    int bid  = blockIdx.x;
    int t    = bid & 255;        // source row / output row-group
    int bc   = bid >> 8;         // fused batch*channel 0..7
    int tid  = threadIdx.x;
    int lane = tid & 63;
    int s    = tid >> 6;         // wave id == vertical phase 0..7

    // --- vertical weights (wave-uniform) ---
    bool hi = (s >= 4);
    float va = s==0?WA0: s==1?WA1: s==2?WA2: s==3?WA3: s==4?WA4: s==5?WA5: s==6?WA6: WA7;
    float vb = s==0?WB0: s==1?WB1: s==2?WB2: s==3?WB3: s==4?WB4: s==5?WB5: s==6?WB6: WB7;
    float ws = s==0?WS0: s==1?WS1: s==2?WS2: s==3?WS3: s==4?WS4: s==5?WS5: s==6?WS6: WS7;
    bool eT = (t == 0)   && !hi;   // rows 0..3 reflect onto source row 0
    bool eB = (t == 255) &&  hi;   // rows 2044..7 reflect onto source row 255
    if (eT || eB) { va = ws; vb = 0.f; }
    int r0 = hi ? t : t - 1;  if (r0 < 0)   r0 = 0;
    int r1 = r0 + 1;          if (r1 > 255) r1 = 255;

    // --- horizontal weights (per-lane constant: parity g&1 == lane&1) ---
    int P = lane & 1;
    float a0 = P ? WA4 : WA0, b0 = P ? WB4 : WB0;
    float a1 = P ? WA5 : WA1, b1 = P ? WB5 : WB1;
    float a2 = P ? WA6 : WA2, b2 = P ? WB6 : WB2;
    float a3 = P ? WA7 : WA3, b3 = P ? WB7 : WB3;
    int cb = (lane >> 1) - 1 + P;      // base source col for step 0

    const float* row0 = img + bc * 65536 + r0 * 256;
    const float* row1 = img + bc * 65536 + r1 * 256;

    // output row i = t*8 + s; lane*16B + step*1KB walks the row contiguously
    float* op = out + (size_t)bc * (2048 * 2048)
                    + ((size_t)(t << 3) + s) * 2048 + (lane << 2);

    #pragma unroll
    for (int st = 0; st < 8; ++st) {
        int g  = (st << 6) | lane;     // float4 group 0..511
        int c0 = cb + (st << 5);
        int c1 = c0 + 1;
        float A0=a0, A1=a1, A2=a2, A3=a3, B0=b0, B1=b1, B2=b2, B3=b3;
        if (st == 0 && g == 0)   { A0=WS0; A1=WS1; A2=WS2; A3=WS3;
                                   B0=B1=B2=B3=0.f; c0=0;   c1=0;   }
        if (st == 7 && g == 511) { A0=WS4; A1=WS5; A2=WS6; A3=WS7;
                                   B0=B1=B2=B3=0.f; c0=255; c1=255; }
        float i0 = row0[c0], i1 = row0[c1];
        float i2 = row1[c0], i3 = row1[c1];
        float u = va * i0 + vb * i2;   // vertical blend, left col
        float w = va * i1 + vb * i3;   // vertical blend, right col
        float4 o;
        o.x = A0 * u + B0 * w;
        o.y = A1 * u + B1 * w;
        o.z = A2 * u + B2 * w;
        o.w = A3 * u + B3 * w;
        *reinterpret_cast<float4*>(op + (st << 8)) = o;
    }
}

extern "C" void kernel_launch(void* const* d_in, const int* in_sizes, int n_in,
                              void* d_out, int out_size, void* d_ws, size_t ws_size,
                              hipStream_t stream) {
    const float* img = (const float*)d_in[0];
    float* out = (float*)d_out;
    dim3 grid(2048), block(512);
    hipLaunchKernelGGL(lanczos_up8_kernel, grid, block, 0, stream, img, out);
}

// Round 7
// 26.125 us; speedup vs baseline: 1.0424x; 1.0424x over previous
//
#include <hip/hip_runtime.h>

// Lanczos-4 8x upsample (4,2,256,256) -> (4,2,2048,2048), fully collapsed
// to a 2x2 stencil with 8 baked weight phases per axis (see R2-R6 history).
//
// R7: exact-residency launch. 1024 blocks x 512 threads = 8 waves/block,
// 4 blocks/CU x 256 CU -> exactly 32 waves/CU in ONE residency round (R5's
// 2048 blocks needed two rounds). Each block emits 2 row-groups = 16 rows
// = one contiguous 128 KB output span. Per-thread body identical to R5
// (best so far: 26.3 us; store-shape variants R2/R5/R6 tie, nt regressed).

// wa (left-column weight), per phase 0..7
#define WA0 0.0f
#define WA1 -0.03041110f
#define WA2 0.02753266f
#define WA3 -0.00827163f
#define WA4 1.00243180f
#define WA5 1.01040147f
#define WA6 0.97375330f
#define WA7 1.03080550f
// wb (right-column weight)
#define WB0 1.0f
#define WB1 1.02991210f
#define WB2 0.97065798f
#define WB3 1.00472265f
#define WB4 -0.00765906f
#define WB5 -0.01652347f
#define WB6 0.02047608f
#define WB7 -0.03455115f
// full tap sum (edge / reflected case: all 9 taps hit one source col/row)
#define WS0 1.0f
#define WS1 0.99950100f
#define WS2 0.99819064f
#define WS3 0.99645102f
#define WS4 0.99477274f
#define WS5 0.99387800f
#define WS6 0.99422938f
#define WS7 0.99625435f

__global__ __launch_bounds__(512) void lanczos_up8_kernel(
    const float* __restrict__ img, float* __restrict__ out)
{
    // grid: bid = bc(8) * 128 + q(128); block covers 2 row-groups (16 rows)
    int bid = blockIdx.x;
    int q   = bid & 127;         // row-group pair 0..127
    int bc  = bid >> 7;          // fused batch*channel 0..7
    int v   = threadIdx.x;       // 4-col output group, 0..511

    int P = v & 1;               // parity: phases 0..3 (P=0) or 4..7 (P=1)
    int m = v >> 1;              // source column group

    bool eL = (v == 0);          // j=0..3   : all taps reflect onto col 0
    bool eR = (v == 511);        // j=2044..7: all taps reflect onto col 255

    // horizontal weights for this lane's 4 phases (all-constant selects)
    float a0 = P ? WA4 : WA0, b0 = P ? WB4 : WB0;
    float a1 = P ? WA5 : WA1, b1 = P ? WB5 : WB1;
    float a2 = P ? WA6 : WA2, b2 = P ? WB6 : WB2;
    float a3 = P ? WA7 : WA3, b3 = P ? WB7 : WB3;
    if (eL) { a0 = WS0; a1 = WS1; a2 = WS2; a3 = WS3; b0 = b1 = b2 = b3 = 0.f; }
    if (eR) { a0 = WS4; a1 = WS5; a2 = WS6; a3 = WS7; b0 = b1 = b2 = b3 = 0.f; }

    int c0 = P ? m : m - 1;
    if (eL) c0 = 0;
    if (eR) c0 = 255;
    int c1 = (eL || eR) ? c0 : c0 + 1;

    const float* base = img + bc * 65536;
    float* outc = out + (size_t)bc * (2048 * 2048);

    #pragma unroll
    for (int k = 0; k < 2; ++k) {
        int t = (q << 1) | k;        // source row / output row-group

        int rm = t > 0   ? t - 1 : 0;    // block-uniform row indices (clamped)
        int rp = t < 255 ? t + 1 : 255;

        float i00 = base[rm * 256 + c0], i01 = base[rm * 256 + c1];
        float i10 = base[t  * 256 + c0], i11 = base[t  * 256 + c1];
        float i20 = base[rp * 256 + c0], i21 = base[rp * 256 + c1];

        // horizontally-filtered values for 3 source rows x 4 output cols
        float h00 = a0*i00 + b0*i01, h01 = a1*i00 + b1*i01, h02 = a2*i00 + b2*i01, h03 = a3*i00 + b3*i01;
        float h10 = a0*i10 + b0*i11, h11 = a1*i10 + b1*i11, h12 = a2*i10 + b2*i11, h13 = a3*i10 + b3*i11;
        float h20 = a0*i20 + b0*i21, h21 = a1*i20 + b1*i21, h22 = a2*i20 + b2*i21, h23 = a3*i20 + b3*i21;

        bool eT = (t == 0);     // rows 0..3   : all taps reflect onto row 0
        bool eB = (t == 255);   // rows 2044..7: all taps reflect onto row 255

        float* op = outc + (size_t)(t << 3) * 2048 + (v << 2);

        float va, vb; float4 o;
        // s<4: rows (t-1, t) -> (h0*, h1*);  s>=4: rows (t, t+1) -> (h1*, h2*)
#define EMIT(S, WAs, WBs, WSs, HX0,HX1,HX2,HX3, HY0,HY1,HY2,HY3, EDGE)   \
        va = (EDGE) ? WSs : WAs;  vb = (EDGE) ? 0.f : WBs;               \
        o.x = va*HX0 + vb*HY0;  o.y = va*HX1 + vb*HY1;                   \
        o.z = va*HX2 + vb*HY2;  o.w = va*HX3 + vb*HY3;                   \
        *reinterpret_cast<float4*>(op + S * 2048) = o;

        EMIT(0, WA0, WB0, WS0, h00,h01,h02,h03, h10,h11,h12,h13, eT)
        EMIT(1, WA1, WB1, WS1, h00,h01,h02,h03, h10,h11,h12,h13, eT)
        EMIT(2, WA2, WB2, WS2, h00,h01,h02,h03, h10,h11,h12,h13, eT)
        EMIT(3, WA3, WB3, WS3, h00,h01,h02,h03, h10,h11,h12,h13, eT)
        EMIT(4, WA4, WB4, WS4, h10,h11,h12,h13, h20,h21,h22,h23, eB)
        EMIT(5, WA5, WB5, WS5, h10,h11,h12,h13, h20,h21,h22,h23, eB)
        EMIT(6, WA6, WB6, WS6, h10,h11,h12,h13, h20,h21,h22,h23, eB)
        EMIT(7, WA7, WB7, WS7, h10,h11,h12,h13, h20,h21,h22,h23, eB)
#undef EMIT
    }
}

extern "C" void kernel_launch(void* const* d_in, const int* in_sizes, int n_in,
                              void* d_out, int out_size, void* d_ws, size_t ws_size,
                              hipStream_t stream) {
    const float* img = (const float*)d_in[0];
    float* out = (float*)d_out;
    dim3 grid(1024), block(512);
    hipLaunchKernelGGL(lanczos_up8_kernel, grid, block, 0, stream, img, out);
}